// Round 1
// baseline (890.449 us; speedup 1.0000x reference)
//
#include <hip/hip_runtime.h>
#include <hip/hip_bf16.h>

#define U_   4096
#define I_   16384
#define D_   64
#define N_   20480      // U_ + I_
#define NEI  524288
#define NES  65536

// ---------------- LightGCN phase ----------------

__global__ void init_kernel(const float* __restrict__ ue, const float* __restrict__ ie,
                            float* __restrict__ h0, float* __restrict__ hs) {
    int tid = blockIdx.x * blockDim.x + threadIdx.x;
    if (tid >= N_ * D_) return;
    float v = (tid < U_ * D_) ? ue[tid] : ie[tid - U_ * D_];
    h0[tid] = v;
    hs[tid] = v;
}

__global__ void count_kernel(const int* __restrict__ rows, int* __restrict__ cnt) {
    int e = blockIdx.x * blockDim.x + threadIdx.x;
    if (e < NEI) atomicAdd(&cnt[rows[e]], 1);
}

// single block of 1024 threads; N_ = 1024*20 exactly
__global__ void scan_kernel(const int* __restrict__ cnt, int* __restrict__ rp, int* __restrict__ offs) {
    __shared__ int part[1024];
    int t = threadIdx.x;
    int base = t * 20;
    int loc[20];
    int s = 0;
    for (int k = 0; k < 20; ++k) { loc[k] = s; s += cnt[base + k]; }
    part[t] = s;
    __syncthreads();
    for (int off = 1; off < 1024; off <<= 1) {
        int v = (t >= off) ? part[t - off] : 0;
        __syncthreads();
        part[t] += v;
        __syncthreads();
    }
    int pre = (t > 0) ? part[t - 1] : 0;
    for (int k = 0; k < 20; ++k) {
        int v = pre + loc[k];
        rp[base + k] = v;
        offs[base + k] = v;
    }
    if (t == 1023) rp[N_] = part[1023];
}

__global__ void scatter_kernel(const int* __restrict__ rows, const int* __restrict__ cols,
                               const float* __restrict__ vals, int* __restrict__ offs,
                               int* __restrict__ cs, float* __restrict__ vs) {
    int e = blockIdx.x * blockDim.x + threadIdx.x;
    if (e >= NEI) return;
    int r = rows[e];
    int pos = atomicAdd(&offs[r], 1);
    cs[pos] = cols[e];
    vs[pos] = vals[e];
}

// one wave per row; lane = embedding dim
__global__ __launch_bounds__(256) void spmm_kernel(const int* __restrict__ rp, const int* __restrict__ cs,
                                                   const float* __restrict__ vs, const float* __restrict__ x,
                                                   float* __restrict__ y, float* __restrict__ hs) {
    int w = (blockIdx.x * blockDim.x + threadIdx.x) >> 6;
    int lane = threadIdx.x & 63;
    if (w >= N_) return;
    int beg = rp[w], end = rp[w + 1];
    float acc = 0.f;
    for (int idx = beg; idx < end; ++idx) {
        int c = cs[idx];
        float v = vs[idx];
        acc += v * x[c * D_ + lane];
    }
    y[w * D_ + lane] = acc;
    hs[w * D_ + lane] += acc;
}

__global__ void usere_kernel(const float* __restrict__ hs, float* __restrict__ user_e) {
    int tid = blockIdx.x * blockDim.x + threadIdx.x;
    if (tid < U_ * D_) user_e[tid] = 0.25f * hs[tid];
}

// ---------------- Social edge-MLP phase ----------------

// Wa2 = Wa @ w1[0:64,:], Wb2 = Wb @ w1[64:128,:]
__global__ void wab2_kernel(const float* __restrict__ Wa, const float* __restrict__ Wb,
                            const float* __restrict__ w1, float* __restrict__ Wa2,
                            float* __restrict__ Wb2) {
    int o = blockIdx.x * blockDim.x + threadIdx.x;   // 8192 total
    if (o >= 2 * 64 * 64) return;
    int mat = o >> 12;
    int i = (o >> 6) & 63;
    int j = o & 63;
    const float* M = mat ? Wb : Wa;
    const float* W1 = w1 + mat * 64 * 64;
    float s = 0.f;
    for (int k = 0; k < 64; ++k) s += M[i * 64 + k] * W1[k * 64 + j];
    (mat ? Wb2 : Wa2)[i * 64 + j] = s;
}

// Pa = user_emb @ Wa2, Pb = user_emb @ Wb2 : one wave per user row
__global__ __launch_bounds__(256) void pab_kernel(const float* __restrict__ ue,
                                                  const float* __restrict__ Wa2,
                                                  const float* __restrict__ Wb2,
                                                  float* __restrict__ Pa, float* __restrict__ Pb) {
    int w = (blockIdx.x * blockDim.x + threadIdx.x) >> 6;
    int lane = threadIdx.x & 63;
    if (w >= U_) return;
    float x = ue[w * 64 + lane];
    float accA = 0.f, accB = 0.f;
    for (int k = 0; k < 64; ++k) {
        float xk = __shfl(x, k);
        accA += xk * Wa2[k * 64 + lane];
        accB += xk * Wb2[k * 64 + lane];
    }
    Pa[w * 64 + lane] = accA;
    Pb[w * 64 + lane] = accB;
}

// one wave per social edge: hid=relu(Pa[c]+Pb[r]+b1); p=hid.w2+b2; A[r,c]+=sigmoid(p)
__global__ __launch_bounds__(256) void edge_kernel(const int* __restrict__ sr, const int* __restrict__ sc,
                                                   const float* __restrict__ Pa, const float* __restrict__ Pb,
                                                   const float* __restrict__ b1, const float* __restrict__ w2,
                                                   const float* __restrict__ b2, float* __restrict__ A) {
    int w = (blockIdx.x * blockDim.x + threadIdx.x) >> 6;
    int lane = threadIdx.x & 63;
    if (w >= NES) return;
    int r = sr[w], c = sc[w];
    float h = Pa[c * 64 + lane] + Pb[r * 64 + lane] + b1[lane];
    h = fmaxf(h, 0.f);
    float t = h * w2[lane];
    for (int o = 32; o > 0; o >>= 1) t += __shfl_down(t, o);
    if (lane == 0) {
        float p = t + b2[0];
        float ew = 1.f / (1.f + expf(-p));
        atomicAdd(&A[(size_t)r * U_ + c], ew);
    }
}

// ---------------- Social diffusion phase ----------------
// block per user row: semb1 = softmax_masked(A[i,:]) @ user_e
//                     semb2 = softmax_masked((A@A)[i,:]) @ user_e  (sparse: ~16 nbrs)
// out[i] = (4*user_e[i] + semb1 + semb2) / 3
__global__ __launch_bounds__(256) void social_kernel(const float* __restrict__ A,
                                                     const float* __restrict__ user_e,
                                                     float* __restrict__ out) {
    __shared__ float p_lds[4096];
    __shared__ float red[256];
    __shared__ float out_acc[4][64];
    __shared__ int klist[256];
    __shared__ float kval[256];
    __shared__ int icnt;

    int i = blockIdx.x;
    int t = threadIdx.x;
    if (t == 0) icnt = 0;
    if (t < 64) { out_acc[0][t] = 0.f; out_acc[1][t] = 0.f; out_acc[2][t] = 0.f; out_acc[3][t] = 0.f; }
    __syncthreads();

    const float* Arow = A + (size_t)i * U_;
    float a[16];
    float mx = -1e30f;
    for (int u = 0; u < 16; ++u) {
        float v = Arow[t + 256 * u];
        a[u] = v;
        if (v > 0.f) {
            mx = fmaxf(mx, v);
            int idx = atomicAdd(&icnt, 1);
            if (idx < 256) { klist[idx] = t + 256 * u; kval[idx] = v; }
        }
    }
    // --- softmax over A row ---
    red[t] = mx; __syncthreads();
    for (int s = 128; s > 0; s >>= 1) { if (t < s) red[t] = fmaxf(red[t], red[t + s]); __syncthreads(); }
    float m = red[0]; __syncthreads();
    float se = 0.f;
    for (int u = 0; u < 16; ++u) {
        float e = (a[u] > 0.f) ? expf(a[u] - m) : 0.f;
        a[u] = e; se += e;
    }
    red[t] = se; __syncthreads();
    for (int s = 128; s > 0; s >>= 1) { if (t < s) red[t] += red[t + s]; __syncthreads(); }
    float inv = (m > 0.f) ? 1.f / red[0] : 0.f;
    __syncthreads();
    for (int u = 0; u < 16; ++u) p_lds[t + 256 * u] = a[u] * inv;
    __syncthreads();
    // weighted sum 1
    {
        int g = t >> 6, d = t & 63;
        float part = 0.f;
        for (int j = g * 1024; j < g * 1024 + 1024; ++j) {
            float pj = p_lds[j];
            if (pj != 0.f) part += pj * user_e[j * 64 + d];
        }
        out_acc[g][d] += part;
    }
    __syncthreads();
    // --- g2 row = sum_k A[i,k] * A[k,:] over nonzero k ---
    int nnz = icnt < 256 ? icnt : 256;
    float b[16];
    for (int u = 0; u < 16; ++u) b[u] = 0.f;
    for (int e2 = 0; e2 < nnz; ++e2) {
        int k = klist[e2];
        float v = kval[e2];
        const float* Ak = A + (size_t)k * U_;
        for (int u = 0; u < 16; ++u) b[u] += v * Ak[t + 256 * u];
    }
    // --- softmax over g2 row ---
    float mx2 = -1e30f;
    for (int u = 0; u < 16; ++u) if (b[u] > 0.f) mx2 = fmaxf(mx2, b[u]);
    red[t] = mx2; __syncthreads();
    for (int s = 128; s > 0; s >>= 1) { if (t < s) red[t] = fmaxf(red[t], red[t + s]); __syncthreads(); }
    float m2 = red[0]; __syncthreads();
    float se2 = 0.f;
    for (int u = 0; u < 16; ++u) {
        float e = (b[u] > 0.f) ? expf(b[u] - m2) : 0.f;
        b[u] = e; se2 += e;
    }
    red[t] = se2; __syncthreads();
    for (int s = 128; s > 0; s >>= 1) { if (t < s) red[t] += red[t + s]; __syncthreads(); }
    float inv2 = (m2 > 0.f) ? 1.f / red[0] : 0.f;
    __syncthreads();
    for (int u = 0; u < 16; ++u) p_lds[t + 256 * u] = b[u] * inv2;
    __syncthreads();
    // weighted sum 2
    {
        int g = t >> 6, d = t & 63;
        float part = 0.f;
        for (int j = g * 1024; j < g * 1024 + 1024; ++j) {
            float pj = p_lds[j];
            if (pj != 0.f) part += pj * user_e[j * 64 + d];
        }
        out_acc[g][d] += part;
    }
    __syncthreads();
    if (t < 64) {
        float s = out_acc[0][t] + out_acc[1][t] + out_acc[2][t] + out_acc[3][t];
        float ue = user_e[i * 64 + t];
        out[i * 64 + t] = (4.f * ue + s) * (1.f / 3.f);
    }
}

// ---------------- Launch ----------------

extern "C" void kernel_launch(void* const* d_in, const int* in_sizes, int n_in,
                              void* d_out, int out_size, void* d_ws, size_t ws_size,
                              hipStream_t stream) {
    (void)in_sizes; (void)n_in; (void)out_size; (void)ws_size;
    const float* user_emb  = (const float*)d_in[0];
    const float* item_emb  = (const float*)d_in[1];
    const float* inter_vals= (const float*)d_in[2];
    const float* Wa        = (const float*)d_in[3];
    const float* Wb        = (const float*)d_in[4];
    const float* w1        = (const float*)d_in[5];
    const float* b1        = (const float*)d_in[6];
    const float* w2        = (const float*)d_in[7];
    const float* b2        = (const float*)d_in[8];
    const int* inter_rows  = (const int*)d_in[9];
    const int* inter_cols  = (const int*)d_in[10];
    const int* social_rows = (const int*)d_in[11];
    const int* social_cols = (const int*)d_in[12];
    float* out = (float*)d_out;

    char* w = (char*)d_ws;
    auto alloc = [&](size_t bytes) -> void* {
        void* p = (void*)w;
        w += (bytes + 255) & ~(size_t)255;
        return p;
    };
    float* h0     = (float*)alloc((size_t)N_ * D_ * 4);
    float* h1     = (float*)alloc((size_t)N_ * D_ * 4);
    float* hs     = (float*)alloc((size_t)N_ * D_ * 4);
    float* user_e = (float*)alloc((size_t)U_ * D_ * 4);
    float* Pa     = (float*)alloc((size_t)U_ * D_ * 4);
    float* Pb     = (float*)alloc((size_t)U_ * D_ * 4);
    float* Wa2    = (float*)alloc(64 * 64 * 4);
    float* Wb2    = (float*)alloc(64 * 64 * 4);
    int*   cnt    = (int*)alloc((N_ + 1) * 4);
    int*   rp     = (int*)alloc((N_ + 1) * 4);
    int*   offs   = (int*)alloc(N_ * 4);
    int*   cs     = (int*)alloc((size_t)NEI * 4);
    float* vs     = (float*)alloc((size_t)NEI * 4);
    float* A      = (float*)alloc((size_t)U_ * U_ * 4);

    hipMemsetAsync(cnt, 0, (N_ + 1) * 4, stream);
    hipMemsetAsync(A, 0, (size_t)U_ * U_ * 4, stream);

    // LightGCN
    init_kernel<<<(N_ * D_ + 255) / 256, 256, 0, stream>>>(user_emb, item_emb, h0, hs);
    count_kernel<<<NEI / 256, 256, 0, stream>>>(inter_rows, cnt);
    scan_kernel<<<1, 1024, 0, stream>>>(cnt, rp, offs);
    scatter_kernel<<<NEI / 256, 256, 0, stream>>>(inter_rows, inter_cols, inter_vals, offs, cs, vs);
    spmm_kernel<<<N_ * 64 / 256, 256, 0, stream>>>(rp, cs, vs, h0, h1, hs);
    spmm_kernel<<<N_ * 64 / 256, 256, 0, stream>>>(rp, cs, vs, h1, h0, hs);
    spmm_kernel<<<N_ * 64 / 256, 256, 0, stream>>>(rp, cs, vs, h0, h1, hs);
    usere_kernel<<<U_ * D_ / 256, 256, 0, stream>>>(hs, user_e);

    // social edge MLP -> dense A
    wab2_kernel<<<(2 * 64 * 64) / 256, 256, 0, stream>>>(Wa, Wb, w1, Wa2, Wb2);
    pab_kernel<<<U_ * 64 / 256, 256, 0, stream>>>(user_emb, Wa2, Wb2, Pa, Pb);
    edge_kernel<<<NES * 64 / 256, 256, 0, stream>>>(social_rows, social_cols, Pa, Pb, b1, w2, b2, A);

    // social diffusion + output
    social_kernel<<<U_, 256, 0, stream>>>(A, user_e, out);
}

// Round 2
// 449.263 us; speedup vs baseline: 1.9820x; 1.9820x over previous
//
#include <hip/hip_runtime.h>
#include <hip/hip_bf16.h>

#define U_   4096
#define I_   16384
#define D_   64
#define N_   20480      // U_ + I_
#define NEI  524288
#define NES  65536
#define RCAP 128        // per-row social nnz capacity (Poisson(16); P(>=128) ~ 0)
#define L2CAP 2048      // g2-row nnz capacity (sum of ~16 Poisson(16) lists)

// ---------------- LightGCN phase ----------------

__global__ void init_kernel(const float* __restrict__ ue, const float* __restrict__ ie,
                            float* __restrict__ h0, float* __restrict__ hs) {
    int tid = blockIdx.x * blockDim.x + threadIdx.x;
    if (tid >= N_ * D_) return;
    float v = (tid < U_ * D_) ? ue[tid] : ie[tid - U_ * D_];
    h0[tid] = v;
    hs[tid] = v;
}

__global__ void count_kernel(const int* __restrict__ rows, int* __restrict__ cnt) {
    int e = blockIdx.x * blockDim.x + threadIdx.x;
    if (e < NEI) atomicAdd(&cnt[rows[e]], 1);
}

// single block of 1024 threads; N_ = 1024*20 exactly
__global__ void scan_kernel(const int* __restrict__ cnt, int* __restrict__ rp, int* __restrict__ offs) {
    __shared__ int part[1024];
    int t = threadIdx.x;
    int base = t * 20;
    int loc[20];
    int s = 0;
    for (int k = 0; k < 20; ++k) { loc[k] = s; s += cnt[base + k]; }
    part[t] = s;
    __syncthreads();
    for (int off = 1; off < 1024; off <<= 1) {
        int v = (t >= off) ? part[t - off] : 0;
        __syncthreads();
        part[t] += v;
        __syncthreads();
    }
    int pre = (t > 0) ? part[t - 1] : 0;
    for (int k = 0; k < 20; ++k) {
        int v = pre + loc[k];
        rp[base + k] = v;
        offs[base + k] = v;
    }
    if (t == 1023) rp[N_] = part[1023];
}

__global__ void scatter_kernel(const int* __restrict__ rows, const int* __restrict__ cols,
                               const float* __restrict__ vals, int* __restrict__ offs,
                               int* __restrict__ cs, float* __restrict__ vs) {
    int e = blockIdx.x * blockDim.x + threadIdx.x;
    if (e >= NEI) return;
    int r = rows[e];
    int pos = atomicAdd(&offs[r], 1);
    cs[pos] = cols[e];
    vs[pos] = vals[e];
}

// one wave per row; lane = embedding dim
__global__ __launch_bounds__(256) void spmm_kernel(const int* __restrict__ rp, const int* __restrict__ cs,
                                                   const float* __restrict__ vs, const float* __restrict__ x,
                                                   float* __restrict__ y, float* __restrict__ hs) {
    int w = (blockIdx.x * blockDim.x + threadIdx.x) >> 6;
    int lane = threadIdx.x & 63;
    if (w >= N_) return;
    int beg = rp[w], end = rp[w + 1];
    float acc = 0.f;
    for (int idx = beg; idx < end; ++idx) {
        int c = cs[idx];
        float v = vs[idx];
        acc += v * x[c * D_ + lane];
    }
    y[w * D_ + lane] = acc;
    hs[w * D_ + lane] += acc;
}

__global__ void usere_kernel(const float* __restrict__ hs, float* __restrict__ user_e) {
    int tid = blockIdx.x * blockDim.x + threadIdx.x;
    if (tid < U_ * D_) user_e[tid] = 0.25f * hs[tid];
}

// ---------------- Social edge-MLP phase ----------------

// Wa2 = Wa @ w1[0:64,:], Wb2 = Wb @ w1[64:128,:]
__global__ void wab2_kernel(const float* __restrict__ Wa, const float* __restrict__ Wb,
                            const float* __restrict__ w1, float* __restrict__ Wa2,
                            float* __restrict__ Wb2) {
    int o = blockIdx.x * blockDim.x + threadIdx.x;   // 8192 total
    if (o >= 2 * 64 * 64) return;
    int mat = o >> 12;
    int i = (o >> 6) & 63;
    int j = o & 63;
    const float* M = mat ? Wb : Wa;
    const float* W1 = w1 + mat * 64 * 64;
    float s = 0.f;
    for (int k = 0; k < 64; ++k) s += M[i * 64 + k] * W1[k * 64 + j];
    (mat ? Wb2 : Wa2)[i * 64 + j] = s;
}

// Pa = user_emb @ Wa2, Pb = user_emb @ Wb2 : one wave per user row
__global__ __launch_bounds__(256) void pab_kernel(const float* __restrict__ ue,
                                                  const float* __restrict__ Wa2,
                                                  const float* __restrict__ Wb2,
                                                  float* __restrict__ Pa, float* __restrict__ Pb) {
    int w = (blockIdx.x * blockDim.x + threadIdx.x) >> 6;
    int lane = threadIdx.x & 63;
    if (w >= U_) return;
    float x = ue[w * 64 + lane];
    float accA = 0.f, accB = 0.f;
    for (int k = 0; k < 64; ++k) {
        float xk = __shfl(x, k);
        accA += xk * Wa2[k * 64 + lane];
        accB += xk * Wb2[k * 64 + lane];
    }
    Pa[w * 64 + lane] = accA;
    Pb[w * 64 + lane] = accB;
}

// one wave per social edge: hid=relu(Pa[c]+Pb[r]+b1); p=hid.w2+b2; A[r,c]+=sigmoid(p)
// First-toucher of a cell (atomic old==0) appends col to the row's sparse list.
__global__ __launch_bounds__(256) void edge_kernel(const int* __restrict__ sr, const int* __restrict__ sc,
                                                   const float* __restrict__ Pa, const float* __restrict__ Pb,
                                                   const float* __restrict__ b1, const float* __restrict__ w2,
                                                   const float* __restrict__ b2, float* __restrict__ A,
                                                   int* __restrict__ scol, int* __restrict__ scnt) {
    int w = (blockIdx.x * blockDim.x + threadIdx.x) >> 6;
    int lane = threadIdx.x & 63;
    if (w >= NES) return;
    int r = sr[w], c = sc[w];
    float h = Pa[c * 64 + lane] + Pb[r * 64 + lane] + b1[lane];
    h = fmaxf(h, 0.f);
    float t = h * w2[lane];
    for (int o = 32; o > 0; o >>= 1) t += __shfl_down(t, o);
    if (lane == 0) {
        float p = t + b2[0];
        float ew = 1.f / (1.f + expf(-p));
        float old = atomicAdd(&A[(size_t)r * U_ + c], ew);
        if (old == 0.f) {
            int idx = atomicAdd(&scnt[r], 1);
            if (idx < RCAP) scol[(size_t)r * RCAP + idx] = c;
        }
    }
}

// ---------------- Social diffusion phase ----------------

__device__ __forceinline__ float block_reduce_max_(float v, float* red, int t) {
    red[t] = v; __syncthreads();
    for (int s = 128; s > 0; s >>= 1) { if (t < s) red[t] = fmaxf(red[t], red[t + s]); __syncthreads(); }
    float r = red[0]; __syncthreads();
    return r;
}
__device__ __forceinline__ float block_reduce_sum_(float v, float* red, int t) {
    red[t] = v; __syncthreads();
    for (int s = 128; s > 0; s >>= 1) { if (t < s) red[t] += red[t + s]; __syncthreads(); }
    float r = red[0]; __syncthreads();
    return r;
}

// block per user row; fully sparse: row-i softmax over scol/A gathers,
// g2 row accumulated sparsely into a dense LDS scratch with first-touch list.
__global__ __launch_bounds__(256) void social_kernel(const float* __restrict__ A,
                                                     const int* __restrict__ scol,
                                                     const int* __restrict__ scnt,
                                                     const float* __restrict__ user_e,
                                                     float* __restrict__ out) {
    __shared__ float row2[U_];        // 16 KB dense g2 scratch
    __shared__ int   list2[L2CAP];    // 8 KB
    __shared__ float val2[L2CAP];     // 8 KB
    __shared__ float red[256];
    __shared__ int   kcol_s[RCAP];
    __shared__ float kval_s[RCAP];
    __shared__ float kprob[RCAP];
    __shared__ float accw[4][64];
    __shared__ int   cnt2_s;

    int i = blockIdx.x, t = threadIdx.x;
    int wv = t >> 6, lane = t & 63;

    for (int u = t; u < U_; u += 256) row2[u] = 0.f;
    if (t == 0) cnt2_s = 0;
    int nnz = scnt[i];
    if (nnz > RCAP) nnz = RCAP;
    if (t < nnz) {
        int c = scol[(size_t)i * RCAP + t];
        kcol_s[t] = c;
        kval_s[t] = A[(size_t)i * U_ + c];
    }
    __syncthreads();

    // --- softmax over row i (sparse, nnz <= 128 < 256) ---
    float mx = (t < nnz) ? kval_s[t] : -1e30f;
    float m1 = block_reduce_max_(mx, red, t);
    float ex = 0.f;
    if (t < nnz) { ex = expf(kval_s[t] - m1); kprob[t] = ex; }
    float S1 = block_reduce_sum_(ex, red, t);   // barrier publishes kprob too
    float inv1 = (nnz > 0) ? 1.f / S1 : 0.f;

    // --- g2 = sum_k A[i,k] * A[k,:] over sparse neighbor lists ---
    for (int e = wv; e < nnz; e += 4) {
        int k = kcol_s[e];
        float vk = kval_s[e];
        int nk = scnt[k];
        if (nk > RCAP) nk = RCAP;
        const int* ck = scol + (size_t)k * RCAP;
        const float* Ak = A + (size_t)k * U_;
        for (int j = lane; j < nk; j += 64) {
            int c2 = ck[j];
            float addv = vk * Ak[c2];
            float old = atomicAdd(&row2[c2], addv);
            if (old == 0.f) {                       // exactly one first-toucher
                int idx = atomicAdd(&cnt2_s, 1);
                if (idx < L2CAP) list2[idx] = c2;
            }
        }
    }

    // --- weighted sum 1 (independent of row2; no sync needed yet) ---
    float acc = 0.f;
    for (int e = wv; e < nnz; e += 4) {
        float p = kprob[e] * inv1;
        acc += p * user_e[(size_t)kcol_s[e] * 64 + lane];
    }
    __syncthreads();

    int cnt2 = cnt2_s;
    if (cnt2 > L2CAP) cnt2 = L2CAP;
    // --- softmax over g2 nonzeros ---
    float mx2 = -1e30f;
    for (int e = t; e < cnt2; e += 256) mx2 = fmaxf(mx2, row2[list2[e]]);
    float m2 = block_reduce_max_(mx2, red, t);
    float se2 = 0.f;
    for (int e = t; e < cnt2; e += 256) {
        float exv = expf(row2[list2[e]] - m2);
        val2[e] = exv;
        se2 += exv;
    }
    float S2 = block_reduce_sum_(se2, red, t);  // barrier publishes val2
    float inv2 = (cnt2 > 0) ? 1.f / S2 : 0.f;

    // --- weighted sum 2 ---
    for (int e = wv; e < cnt2; e += 4) {
        float p = val2[e] * inv2;
        acc += p * user_e[(size_t)list2[e] * 64 + lane];
    }
    accw[wv][lane] = acc;
    __syncthreads();
    if (t < 64) {
        float s = accw[0][t] + accw[1][t] + accw[2][t] + accw[3][t];
        float ue = user_e[(size_t)i * 64 + t];
        out[i * 64 + t] = (4.f * ue + s) * (1.f / 3.f);
    }
}

// ---------------- Launch ----------------

extern "C" void kernel_launch(void* const* d_in, const int* in_sizes, int n_in,
                              void* d_out, int out_size, void* d_ws, size_t ws_size,
                              hipStream_t stream) {
    (void)in_sizes; (void)n_in; (void)out_size; (void)ws_size;
    const float* user_emb  = (const float*)d_in[0];
    const float* item_emb  = (const float*)d_in[1];
    const float* inter_vals= (const float*)d_in[2];
    const float* Wa        = (const float*)d_in[3];
    const float* Wb        = (const float*)d_in[4];
    const float* w1        = (const float*)d_in[5];
    const float* b1        = (const float*)d_in[6];
    const float* w2        = (const float*)d_in[7];
    const float* b2        = (const float*)d_in[8];
    const int* inter_rows  = (const int*)d_in[9];
    const int* inter_cols  = (const int*)d_in[10];
    const int* social_rows = (const int*)d_in[11];
    const int* social_cols = (const int*)d_in[12];
    float* out = (float*)d_out;

    char* w = (char*)d_ws;
    auto alloc = [&](size_t bytes) -> void* {
        void* p = (void*)w;
        w += (bytes + 255) & ~(size_t)255;
        return p;
    };
    float* h0     = (float*)alloc((size_t)N_ * D_ * 4);
    float* h1     = (float*)alloc((size_t)N_ * D_ * 4);
    float* hs     = (float*)alloc((size_t)N_ * D_ * 4);
    float* user_e = (float*)alloc((size_t)U_ * D_ * 4);
    float* Pa     = (float*)alloc((size_t)U_ * D_ * 4);
    float* Pb     = (float*)alloc((size_t)U_ * D_ * 4);
    float* Wa2    = (float*)alloc(64 * 64 * 4);
    float* Wb2    = (float*)alloc(64 * 64 * 4);
    int*   cnt    = (int*)alloc((N_ + 1) * 4);
    int*   rp     = (int*)alloc((N_ + 1) * 4);
    int*   offs   = (int*)alloc(N_ * 4);
    int*   cs     = (int*)alloc((size_t)NEI * 4);
    float* vs     = (float*)alloc((size_t)NEI * 4);
    int*   scol   = (int*)alloc((size_t)U_ * RCAP * 4);
    int*   scnt   = (int*)alloc((size_t)U_ * 4);
    float* A      = (float*)alloc((size_t)U_ * U_ * 4);

    hipMemsetAsync(cnt, 0, (N_ + 1) * 4, stream);
    hipMemsetAsync(scnt, 0, (size_t)U_ * 4, stream);
    hipMemsetAsync(A, 0, (size_t)U_ * U_ * 4, stream);

    // LightGCN
    init_kernel<<<(N_ * D_ + 255) / 256, 256, 0, stream>>>(user_emb, item_emb, h0, hs);
    count_kernel<<<NEI / 256, 256, 0, stream>>>(inter_rows, cnt);
    scan_kernel<<<1, 1024, 0, stream>>>(cnt, rp, offs);
    scatter_kernel<<<NEI / 256, 256, 0, stream>>>(inter_rows, inter_cols, inter_vals, offs, cs, vs);
    spmm_kernel<<<N_ * 64 / 256, 256, 0, stream>>>(rp, cs, vs, h0, h1, hs);
    spmm_kernel<<<N_ * 64 / 256, 256, 0, stream>>>(rp, cs, vs, h1, h0, hs);
    spmm_kernel<<<N_ * 64 / 256, 256, 0, stream>>>(rp, cs, vs, h0, h1, hs);
    usere_kernel<<<U_ * D_ / 256, 256, 0, stream>>>(hs, user_e);

    // social edge MLP -> dense A + sparse row lists
    wab2_kernel<<<(2 * 64 * 64) / 256, 256, 0, stream>>>(Wa, Wb, w1, Wa2, Wb2);
    pab_kernel<<<U_ * 64 / 256, 256, 0, stream>>>(user_emb, Wa2, Wb2, Pa, Pb);
    edge_kernel<<<NES * 64 / 256, 256, 0, stream>>>(social_rows, social_cols, Pa, Pb, b1, w2, b2,
                                                    A, scol, scnt);

    // social diffusion + output
    social_kernel<<<U_, 256, 0, stream>>>(A, scol, scnt, user_e, out);
}

// Round 3
// 401.131 us; speedup vs baseline: 2.2198x; 1.1200x over previous
//
#include <hip/hip_runtime.h>
#include <hip/hip_bf16.h>

#define U_   4096
#define I_   16384
#define D_   64
#define N_   20480      // U_ + I_
#define NEI  524288
#define NES  65536
#define RCAP 128        // per-row social hash slots (Poisson(16) nnz; max ~45)
#define L2CAP 1024      // g2-row nnz capacity (~256 expected)

// ---------------- LightGCN phase ----------------

__global__ void init_kernel(const float* __restrict__ ue, const float* __restrict__ ie,
                            float* __restrict__ h0, float* __restrict__ hs) {
    int tid = blockIdx.x * blockDim.x + threadIdx.x;
    if (tid >= N_ * D_) return;
    float v = (tid < U_ * D_) ? ue[tid] : ie[tid - U_ * D_];
    h0[tid] = v;
    if (tid < U_ * D_) hs[tid] = v;   // hs only tracks user rows
}

__global__ void count_kernel(const int* __restrict__ rows, int* __restrict__ cnt) {
    int e = blockIdx.x * blockDim.x + threadIdx.x;
    if (e < NEI) atomicAdd(&cnt[rows[e]], 1);
}

// single block of 1024 threads; N_ = 1024*20 exactly
__global__ void scan_kernel(const int* __restrict__ cnt, int* __restrict__ rp, int* __restrict__ offs) {
    __shared__ int part[1024];
    int t = threadIdx.x;
    int base = t * 20;
    int loc[20];
    int s = 0;
    for (int k = 0; k < 20; ++k) { loc[k] = s; s += cnt[base + k]; }
    part[t] = s;
    __syncthreads();
    for (int off = 1; off < 1024; off <<= 1) {
        int v = (t >= off) ? part[t - off] : 0;
        __syncthreads();
        part[t] += v;
        __syncthreads();
    }
    int pre = (t > 0) ? part[t - 1] : 0;
    for (int k = 0; k < 20; ++k) {
        int v = pre + loc[k];
        rp[base + k] = v;
        offs[base + k] = v;
    }
    if (t == 1023) rp[N_] = part[1023];
}

__global__ void scatter_kernel(const int* __restrict__ rows, const int* __restrict__ cols,
                               const float* __restrict__ vals, int* __restrict__ offs,
                               int* __restrict__ cs, float* __restrict__ vs) {
    int e = blockIdx.x * blockDim.x + threadIdx.x;
    if (e >= NEI) return;
    int r = rows[e];
    int pos = atomicAdd(&offs[r], 1);
    cs[pos] = cols[e];
    vs[pos] = vals[e];
}

// one wave per row; lane = dim. Cols/vals loaded coalesced then shfl-broadcast,
// so gathers have no load->load dependency chain.
__global__ __launch_bounds__(256) void spmm_kernel(const int* __restrict__ rp, const int* __restrict__ cs,
                                                   const float* __restrict__ vs, const float* __restrict__ x,
                                                   float* __restrict__ y, float* __restrict__ hs) {
    int w = (blockIdx.x * blockDim.x + threadIdx.x) >> 6;
    int lane = threadIdx.x & 63;
    if (w >= N_) return;
    int beg = rp[w], end = rp[w + 1];
    float acc = 0.f;
    for (int base = beg; base < end; base += 64) {
        int j = base + lane;
        int c = 0; float v = 0.f;
        if (j < end) { c = cs[j]; v = vs[j]; }
        int lim = end - base; if (lim > 64) lim = 64;
        for (int u = 0; u < lim; ++u) {
            int   cu = __shfl(c, u);
            float vu = __shfl(v, u);
            acc += vu * x[(size_t)cu * D_ + lane];
        }
    }
    y[(size_t)w * D_ + lane] = acc;
    if (w < U_) hs[(size_t)w * D_ + lane] += acc;
}

// last LightGCN layer: only user rows needed; fuse user_e = 0.25*(hs+acc)
__global__ __launch_bounds__(256) void spmm_last_kernel(const int* __restrict__ rp, const int* __restrict__ cs,
                                                        const float* __restrict__ vs, const float* __restrict__ x,
                                                        const float* __restrict__ hs, float* __restrict__ user_e) {
    int w = (blockIdx.x * blockDim.x + threadIdx.x) >> 6;
    int lane = threadIdx.x & 63;
    if (w >= U_) return;
    int beg = rp[w], end = rp[w + 1];
    float acc = 0.f;
    for (int base = beg; base < end; base += 64) {
        int j = base + lane;
        int c = 0; float v = 0.f;
        if (j < end) { c = cs[j]; v = vs[j]; }
        int lim = end - base; if (lim > 64) lim = 64;
        for (int u = 0; u < lim; ++u) {
            int   cu = __shfl(c, u);
            float vu = __shfl(v, u);
            acc += vu * x[(size_t)cu * D_ + lane];
        }
    }
    user_e[(size_t)w * D_ + lane] = 0.25f * (hs[(size_t)w * D_ + lane] + acc);
}

// ---------------- Social edge-MLP phase ----------------

// Pa = user_emb @ (Wa @ w1_top), Pb = user_emb @ (Wb @ w1_bot)
// Folded weights computed per block into LDS (redundant but tiny).
__global__ __launch_bounds__(256) void pab_kernel(const float* __restrict__ ue,
                                                  const float* __restrict__ Wa,
                                                  const float* __restrict__ Wb,
                                                  const float* __restrict__ w1,
                                                  float* __restrict__ Pa, float* __restrict__ Pb) {
    __shared__ float Wa2[64 * 64];
    __shared__ float Wb2[64 * 64];
    int t = threadIdx.x;
    for (int o = t; o < 2 * 64 * 64; o += 256) {
        int mat = o >> 12;
        int i = (o >> 6) & 63;
        int j = o & 63;
        const float* M  = mat ? Wb : Wa;
        const float* W1 = w1 + mat * 64 * 64;
        float s = 0.f;
        #pragma unroll 8
        for (int k = 0; k < 64; ++k) s += M[i * 64 + k] * W1[k * 64 + j];
        (mat ? Wb2 : Wa2)[i * 64 + j] = s;
    }
    __syncthreads();
    int wv = t >> 6, lane = t & 63;
    int r0 = blockIdx.x * 16;                  // 256 blocks x 16 rows
    for (int rr = wv; rr < 16; rr += 4) {
        int w = r0 + rr;
        float x = ue[w * 64 + lane];
        float accA = 0.f, accB = 0.f;
        for (int k = 0; k < 64; ++k) {
            float xk = __shfl(x, k);
            accA += xk * Wa2[k * 64 + lane];
            accB += xk * Wb2[k * 64 + lane];
        }
        Pa[w * 64 + lane] = accA;
        Pb[w * 64 + lane] = accB;
    }
}

// one wave per social edge: hid=relu(Pa[c]+Pb[r]+b1); p=hid.w2+b2;
// insert sigmoid(p) into row r's hash (CAS key + atomicAdd val handles dups).
__global__ __launch_bounds__(256) void edge_kernel(const int* __restrict__ sr, const int* __restrict__ sc,
                                                   const float* __restrict__ Pa, const float* __restrict__ Pb,
                                                   const float* __restrict__ b1, const float* __restrict__ w2,
                                                   const float* __restrict__ b2,
                                                   int* __restrict__ skey, float* __restrict__ sval) {
    int w = (blockIdx.x * blockDim.x + threadIdx.x) >> 6;
    int lane = threadIdx.x & 63;
    if (w >= NES) return;
    int r = sr[w], c = sc[w];
    float h = Pa[c * 64 + lane] + Pb[r * 64 + lane] + b1[lane];
    h = fmaxf(h, 0.f);
    float t = h * w2[lane];
    for (int o = 32; o > 0; o >>= 1) t += __shfl_down(t, o);
    if (lane == 0) {
        float p = t + b2[0];
        float ew = 1.f / (1.f + expf(-p));
        size_t base = (size_t)r * RCAP;
        int hh = c & (RCAP - 1);
        for (int probe = 0; probe < RCAP; ++probe) {
            int prev = atomicCAS(&skey[base + hh], -1, c);
            if (prev == -1 || prev == c) { atomicAdd(&sval[base + hh], ew); break; }
            hh = (hh + 1) & (RCAP - 1);
        }
    }
}

// ---------------- Social diffusion phase ----------------

__device__ __forceinline__ float block_reduce_max_(float v, float* red, int t) {
    red[t] = v; __syncthreads();
    for (int s = 128; s > 0; s >>= 1) { if (t < s) red[t] = fmaxf(red[t], red[t + s]); __syncthreads(); }
    float r = red[0]; __syncthreads();
    return r;
}
__device__ __forceinline__ float block_reduce_sum_(float v, float* red, int t) {
    red[t] = v; __syncthreads();
    for (int s = 128; s > 0; s >>= 1) { if (t < s) red[t] += red[t + s]; __syncthreads(); }
    float r = red[0]; __syncthreads();
    return r;
}

// block per user row; everything sparse via the hash rows (L2-resident).
__global__ __launch_bounds__(256) void social_kernel(const int* __restrict__ skey,
                                                     const float* __restrict__ sval,
                                                     const float* __restrict__ user_e,
                                                     float* __restrict__ out) {
    __shared__ float row2[U_];        // 16 KB dense g2 scratch
    __shared__ int   list2[L2CAP];    // 4 KB
    __shared__ float val2[L2CAP];     // 4 KB
    __shared__ float red[256];
    __shared__ int   kcol_s[RCAP];
    __shared__ float kval_s[RCAP];
    __shared__ float kprob[RCAP];
    __shared__ float accw[4][64];
    __shared__ int   cnt_s, cnt2_s;

    int i = blockIdx.x, t = threadIdx.x;
    int wv = t >> 6, lane = t & 63;

    for (int u = t; u < U_; u += 256) row2[u] = 0.f;
    if (t == 0) { cnt_s = 0; cnt2_s = 0; }
    __syncthreads();

    // compact row i's hash into kcol_s/kval_s
    if (t < RCAP) {
        int k = skey[(size_t)i * RCAP + t];
        if (k >= 0) {
            int idx = atomicAdd(&cnt_s, 1);
            kcol_s[idx] = k;
            kval_s[idx] = sval[(size_t)i * RCAP + t];
        }
    }
    __syncthreads();
    int nnz = cnt_s;   // <= ~45 << RCAP

    // --- softmax over row i ---
    float mx = (t < nnz) ? kval_s[t] : -1e30f;
    float m1 = block_reduce_max_(mx, red, t);
    float ex = 0.f;
    if (t < nnz) { ex = expf(kval_s[t] - m1); kprob[t] = ex; }
    float S1 = block_reduce_sum_(ex, red, t);   // barrier publishes kprob
    float inv1 = (nnz > 0) ? 1.f / S1 : 0.f;

    // --- g2 = sum_k A[i,k] * A[k,:] via neighbor hash rows ---
    for (int e = wv; e < nnz; e += 4) {
        int k = kcol_s[e];
        float vk = kval_s[e];
        const int*   kk = skey + (size_t)k * RCAP;
        const float* kv = sval + (size_t)k * RCAP;
        #pragma unroll
        for (int s = 0; s < RCAP; s += 64) {
            int c2 = kk[s + lane];
            if (c2 >= 0) {
                float old = atomicAdd(&row2[c2], vk * kv[s + lane]);
                if (old == 0.f) {                 // exactly one first-toucher
                    int idx = atomicAdd(&cnt2_s, 1);
                    if (idx < L2CAP) list2[idx] = c2;
                }
            }
        }
    }

    // --- weighted sum 1 (independent of row2; no sync needed yet) ---
    float acc = 0.f;
    for (int e = wv; e < nnz; e += 4) {
        float p = kprob[e] * inv1;
        acc += p * user_e[(size_t)kcol_s[e] * 64 + lane];
    }
    __syncthreads();

    int cnt2 = cnt2_s;
    if (cnt2 > L2CAP) cnt2 = L2CAP;
    // --- softmax over g2 nonzeros ---
    float mx2 = -1e30f;
    for (int e = t; e < cnt2; e += 256) mx2 = fmaxf(mx2, row2[list2[e]]);
    float m2 = block_reduce_max_(mx2, red, t);
    float se2 = 0.f;
    for (int e = t; e < cnt2; e += 256) {
        float exv = expf(row2[list2[e]] - m2);
        val2[e] = exv;
        se2 += exv;
    }
    float S2 = block_reduce_sum_(se2, red, t);  // barrier publishes val2
    float inv2 = (cnt2 > 0) ? 1.f / S2 : 0.f;

    // --- weighted sum 2 ---
    for (int e = wv; e < cnt2; e += 4) {
        float p = val2[e] * inv2;
        acc += p * user_e[(size_t)list2[e] * 64 + lane];
    }
    accw[wv][lane] = acc;
    __syncthreads();
    if (t < 64) {
        float s = accw[0][t] + accw[1][t] + accw[2][t] + accw[3][t];
        float ue = user_e[(size_t)i * 64 + t];
        out[i * 64 + t] = (4.f * ue + s) * (1.f / 3.f);
    }
}

// ---------------- Launch ----------------

extern "C" void kernel_launch(void* const* d_in, const int* in_sizes, int n_in,
                              void* d_out, int out_size, void* d_ws, size_t ws_size,
                              hipStream_t stream) {
    (void)in_sizes; (void)n_in; (void)out_size; (void)ws_size;
    const float* user_emb  = (const float*)d_in[0];
    const float* item_emb  = (const float*)d_in[1];
    const float* inter_vals= (const float*)d_in[2];
    const float* Wa        = (const float*)d_in[3];
    const float* Wb        = (const float*)d_in[4];
    const float* w1        = (const float*)d_in[5];
    const float* b1        = (const float*)d_in[6];
    const float* w2        = (const float*)d_in[7];
    const float* b2        = (const float*)d_in[8];
    const int* inter_rows  = (const int*)d_in[9];
    const int* inter_cols  = (const int*)d_in[10];
    const int* social_rows = (const int*)d_in[11];
    const int* social_cols = (const int*)d_in[12];
    float* out = (float*)d_out;

    char* w = (char*)d_ws;
    auto alloc = [&](size_t bytes) -> void* {
        void* p = (void*)w;
        w += (bytes + 255) & ~(size_t)255;
        return p;
    };
    float* h0     = (float*)alloc((size_t)N_ * D_ * 4);
    float* h1     = (float*)alloc((size_t)N_ * D_ * 4);
    float* hs     = (float*)alloc((size_t)U_ * D_ * 4);
    float* user_e = (float*)alloc((size_t)U_ * D_ * 4);
    float* Pa     = (float*)alloc((size_t)U_ * D_ * 4);
    float* Pb     = (float*)alloc((size_t)U_ * D_ * 4);
    int*   cnt    = (int*)alloc((N_ + 1) * 4);
    int*   rp     = (int*)alloc((N_ + 1) * 4);
    int*   offs   = (int*)alloc(N_ * 4);
    int*   cs     = (int*)alloc((size_t)NEI * 4);
    float* vs     = (float*)alloc((size_t)NEI * 4);
    int*   skey   = (int*)alloc((size_t)U_ * RCAP * 4);
    float* sval   = (float*)alloc((size_t)U_ * RCAP * 4);

    hipMemsetAsync(cnt, 0, (N_ + 1) * 4, stream);
    hipMemsetAsync(skey, 0xFF, (size_t)U_ * RCAP * 4, stream);   // keys = -1
    hipMemsetAsync(sval, 0, (size_t)U_ * RCAP * 4, stream);

    // LightGCN
    init_kernel<<<(N_ * D_ + 255) / 256, 256, 0, stream>>>(user_emb, item_emb, h0, hs);
    count_kernel<<<NEI / 256, 256, 0, stream>>>(inter_rows, cnt);
    scan_kernel<<<1, 1024, 0, stream>>>(cnt, rp, offs);
    scatter_kernel<<<NEI / 256, 256, 0, stream>>>(inter_rows, inter_cols, inter_vals, offs, cs, vs);
    spmm_kernel<<<N_ * 64 / 256, 256, 0, stream>>>(rp, cs, vs, h0, h1, hs);
    spmm_kernel<<<N_ * 64 / 256, 256, 0, stream>>>(rp, cs, vs, h1, h0, hs);
    spmm_last_kernel<<<U_ * 64 / 256, 256, 0, stream>>>(rp, cs, vs, h0, hs, user_e);

    // social edge MLP -> sparse hash rows
    pab_kernel<<<U_ / 16, 256, 0, stream>>>(user_emb, Wa, Wb, w1, Pa, Pb);
    edge_kernel<<<NES * 64 / 256, 256, 0, stream>>>(social_rows, social_cols, Pa, Pb, b1, w2, b2,
                                                    skey, sval);

    // social diffusion + output
    social_kernel<<<U_, 256, 0, stream>>>(skey, sval, user_e, out);
}

// Round 4
// 277.435 us; speedup vs baseline: 3.2096x; 1.4459x over previous
//
#include <hip/hip_runtime.h>
#include <hip/hip_bf16.h>

#define U_    4096
#define I_    16384
#define D_    64
#define N_    20480     // U_ + I_
#define NEI   524288
#define NES   65536
#define CAPI  96        // interaction row-bucket capacity (mean 25.6; P(>=96) ~ 4e-25)
#define RCAPS 64        // social hash slots/row (mean nnz 16, max ~45; P(>=64) ~ 1e-18)
#define L2CAP 1536      // g2-row unique-col capacity (mean ~256, max ~800)

// ---------------- LightGCN: bucketed edge build ----------------

// One pass: slot = atomicAdd(count) doubles as CSR build + count.
__global__ void scatter_i_kernel(const int* __restrict__ rows, const int* __restrict__ cols,
                                 const float* __restrict__ vals,
                                 int* __restrict__ cnt, int2* __restrict__ ed) {
    int e = blockIdx.x * 256 + threadIdx.x;
    if (e >= NEI) return;
    int r = rows[e];
    int pos = atomicAdd(&cnt[r], 1);
    if (pos < CAPI) ed[(size_t)r * CAPI + pos] = make_int2(cols[e], __float_as_int(vals[e]));
}

// wave per row, lane = dim; per edge: wave-uniform int2 broadcast load + coalesced row gather.
__global__ __launch_bounds__(256) void spmm1_kernel(const int* __restrict__ cnt, const int2* __restrict__ ed,
                                                    const float* __restrict__ ue, const float* __restrict__ ie,
                                                    float* __restrict__ h1) {
    int w = (blockIdx.x * 256 + threadIdx.x) >> 6;
    int lane = threadIdx.x & 63;
    if (w >= N_) return;
    int n = cnt[w]; if (n > CAPI) n = CAPI;
    const int2* row = ed + (size_t)w * CAPI;
    float acc = 0.f;
    #pragma unroll 4
    for (int j = 0; j < n; ++j) {
        int2 e = row[j];
        int c = e.x; float v = __int_as_float(e.y);
        const float* xp = (c < U_) ? (ue + (size_t)c * D_) : (ie + (size_t)(c - U_) * D_);
        acc += v * xp[lane];
    }
    h1[(size_t)w * D_ + lane] = acc;
}

__global__ __launch_bounds__(256) void spmm2_kernel(const int* __restrict__ cnt, const int2* __restrict__ ed,
                                                    const float* __restrict__ x, float* __restrict__ y) {
    int w = (blockIdx.x * 256 + threadIdx.x) >> 6;
    int lane = threadIdx.x & 63;
    if (w >= N_) return;
    int n = cnt[w]; if (n > CAPI) n = CAPI;
    const int2* row = ed + (size_t)w * CAPI;
    float acc = 0.f;
    #pragma unroll 4
    for (int j = 0; j < n; ++j) {
        int2 e = row[j];
        acc += __int_as_float(e.y) * x[(size_t)e.x * D_ + lane];
    }
    y[(size_t)w * D_ + lane] = acc;
}

// layer 3: only user rows consumed; fuse user_e = 0.25*(e0+e1+e2+e3)
__global__ __launch_bounds__(256) void spmm_last_kernel(const int* __restrict__ cnt, const int2* __restrict__ ed,
                                                        const float* __restrict__ ue,
                                                        const float* __restrict__ h1, const float* __restrict__ h2,
                                                        float* __restrict__ user_e) {
    int w = (blockIdx.x * 256 + threadIdx.x) >> 6;
    int lane = threadIdx.x & 63;
    if (w >= U_) return;
    int n = cnt[w]; if (n > CAPI) n = CAPI;
    const int2* row = ed + (size_t)w * CAPI;
    float acc = 0.f;
    #pragma unroll 4
    for (int j = 0; j < n; ++j) {
        int2 e = row[j];
        acc += __int_as_float(e.y) * h2[(size_t)e.x * D_ + lane];
    }
    size_t o = (size_t)w * D_ + lane;
    user_e[o] = 0.25f * (ue[o] + h1[o] + h2[o] + acc);
}

// ---------------- Social edge-MLP phase ----------------

// Pa = user_emb @ (Wa @ w1_top), Pb = user_emb @ (Wb @ w1_bot); folded weights per block.
__global__ __launch_bounds__(256) void pab_kernel(const float* __restrict__ ue,
                                                  const float* __restrict__ Wa,
                                                  const float* __restrict__ Wb,
                                                  const float* __restrict__ w1,
                                                  float* __restrict__ Pa, float* __restrict__ Pb) {
    __shared__ float Wa2[64 * 64];
    __shared__ float Wb2[64 * 64];
    int t = threadIdx.x;
    for (int o = t; o < 2 * 64 * 64; o += 256) {
        int mat = o >> 12;
        int i = (o >> 6) & 63;
        int j = o & 63;
        const float* M  = mat ? Wb : Wa;
        const float* W1 = w1 + mat * 64 * 64;
        float s = 0.f;
        #pragma unroll 8
        for (int k = 0; k < 64; ++k) s += M[i * 64 + k] * W1[k * 64 + j];
        (mat ? Wb2 : Wa2)[i * 64 + j] = s;
    }
    __syncthreads();
    int wv = t >> 6, lane = t & 63;
    int r0 = blockIdx.x * 16;                  // 256 blocks x 16 rows
    for (int rr = wv; rr < 16; rr += 4) {
        int w = r0 + rr;
        float x = ue[w * 64 + lane];
        float accA = 0.f, accB = 0.f;
        for (int k = 0; k < 64; ++k) {
            float xk = __shfl(x, k);
            accA += xk * Wa2[k * 64 + lane];
            accB += xk * Wb2[k * 64 + lane];
        }
        Pa[w * 64 + lane] = accA;
        Pb[w * 64 + lane] = accB;
    }
}

// 16 lanes per edge, float4: hid=relu(Pa[c]+Pb[r]+b1); p=hid.w2+b2; hash-insert sigmoid(p).
__global__ __launch_bounds__(256) void edge_kernel(const int* __restrict__ sr, const int* __restrict__ sc,
                                                   const float* __restrict__ Pa, const float* __restrict__ Pb,
                                                   const float* __restrict__ b1, const float* __restrict__ w2,
                                                   const float* __restrict__ b2,
                                                   int* __restrict__ skey, float* __restrict__ sval) {
    int gid = blockIdx.x * 256 + threadIdx.x;
    int w = gid >> 4;
    int q = gid & 15;
    if (w >= NES) return;
    int r = sr[w], c = sc[w];
    float4 pa = ((const float4*)Pa)[c * 16 + q];
    float4 pb = ((const float4*)Pb)[r * 16 + q];
    float4 bb = ((const float4*)b1)[q];
    float4 ww = ((const float4*)w2)[q];
    float hx = fmaxf(pa.x + pb.x + bb.x, 0.f);
    float hy = fmaxf(pa.y + pb.y + bb.y, 0.f);
    float hz = fmaxf(pa.z + pb.z + bb.z, 0.f);
    float hw = fmaxf(pa.w + pb.w + bb.w, 0.f);
    float t = hx * ww.x + hy * ww.y + hz * ww.z + hw * ww.w;
    t += __shfl_xor(t, 8);
    t += __shfl_xor(t, 4);
    t += __shfl_xor(t, 2);
    t += __shfl_xor(t, 1);
    if (q == 0) {
        float p = t + b2[0];
        float ew = 1.f / (1.f + expf(-p));
        size_t base = (size_t)r * RCAPS;
        int hh = c & (RCAPS - 1);
        for (int probe = 0; probe < RCAPS; ++probe) {
            int prev = atomicCAS(&skey[base + hh], -1, c);
            if (prev == -1 || prev == c) { atomicAdd(&sval[base + hh], ew); break; }
            hh = (hh + 1) & (RCAPS - 1);
        }
    }
}

// ---------------- Social diffusion phase ----------------

__device__ __forceinline__ float wave_max_(float v) {
    #pragma unroll
    for (int o = 32; o > 0; o >>= 1) v = fmaxf(v, __shfl_xor(v, o));
    return v;
}
__device__ __forceinline__ float wave_sum_(float v) {
    #pragma unroll
    for (int o = 32; o > 0; o >>= 1) v += __shfl_xor(v, o);
    return v;
}

// block per user row; ballot compaction, per-wave shfl softmax1 (0 barriers),
// 2-barrier softmax2. ~5 barriers total.
__global__ __launch_bounds__(256) void social_kernel(const int* __restrict__ skey,
                                                     const float* __restrict__ sval,
                                                     const float* __restrict__ user_e,
                                                     float* __restrict__ out) {
    __shared__ float row2[U_];        // 16 KB dense g2 scratch
    __shared__ int   list2[L2CAP];    // 6 KB
    __shared__ float val2[L2CAP];     // 6 KB
    __shared__ int   kcol_s[RCAPS];
    __shared__ float kval_s[RCAPS];
    __shared__ float wredm[4], wreds[4];
    __shared__ float accw[4][64];
    __shared__ int   cnt2_s, nnz_s;

    int i = blockIdx.x, t = threadIdx.x;
    int wv = t >> 6, lane = t & 63;

    for (int u = t; u < U_; u += 256) row2[u] = 0.f;
    if (t == 0) cnt2_s = 0;

    // wave 0: ballot-compact row i's hash (no atomics, no tree)
    if (wv == 0) {
        int k = skey[(size_t)i * RCAPS + lane];
        float v = sval[(size_t)i * RCAPS + lane];
        unsigned long long mask = __ballot(k >= 0);
        int pos = __popcll(mask & ((1ull << lane) - 1ull));
        if (k >= 0) { kcol_s[pos] = k; kval_s[pos] = v; }
        if (lane == 0) nnz_s = __popcll(mask);
    }
    __syncthreads();                                  // barrier 1
    int nnz = nnz_s;

    // per-wave redundant softmax1 (registers + shfl, zero barriers); nnz <= ~45 < 64
    float kv  = (lane < nnz) ? kval_s[lane] : -1e30f;
    float m1  = wave_max_(kv);
    float ex  = (lane < nnz) ? expf(kv - m1) : 0.f;
    float S1  = wave_sum_(ex);
    float inv1 = (nnz > 0) ? 1.f / S1 : 0.f;

    // g2 = sum_k A[i,k] * A[k,:] via neighbor hash rows (one 64-lane pass each)
    for (int e = wv; e < nnz; e += 4) {
        int k = kcol_s[e];
        float vk = kval_s[e];
        int   c2 = skey[(size_t)k * RCAPS + lane];
        float v2 = sval[(size_t)k * RCAPS + lane];
        if (c2 >= 0) {
            float old = atomicAdd(&row2[c2], vk * v2);
            if (old == 0.f) {                       // exactly one first-toucher
                int idx = atomicAdd(&cnt2_s, 1);
                if (idx < L2CAP) list2[idx] = c2;
            }
        }
    }

    // weighted sum 1 (independent of row2)
    float acc = 0.f;
    for (int e = wv; e < nnz; e += 4) {
        float p = __shfl(ex, e) * inv1;
        acc += p * user_e[(size_t)kcol_s[e] * D_ + lane];
    }
    __syncthreads();                                  // barrier 2 (g2 complete)

    int cnt2 = cnt2_s;
    if (cnt2 > L2CAP) cnt2 = L2CAP;

    // softmax2: per-thread partials + wave shfl + 4-entry cross-wave combine
    float lm = -1e30f;
    for (int e = t; e < cnt2; e += 256) lm = fmaxf(lm, row2[list2[e]]);
    lm = wave_max_(lm);
    if (lane == 0) wredm[wv] = lm;
    __syncthreads();                                  // barrier 3
    float m2 = fmaxf(fmaxf(wredm[0], wredm[1]), fmaxf(wredm[2], wredm[3]));
    float ls = 0.f;
    for (int e = t; e < cnt2; e += 256) {
        float exv = expf(row2[list2[e]] - m2);
        val2[e] = exv;
        ls += exv;
    }
    ls = wave_sum_(ls);
    if (lane == 0) wreds[wv] = ls;
    __syncthreads();                                  // barrier 4 (publishes val2)
    float S2 = wreds[0] + wreds[1] + wreds[2] + wreds[3];
    float inv2 = (cnt2 > 0) ? 1.f / S2 : 0.f;

    // weighted sum 2
    #pragma unroll 4
    for (int e = wv; e < cnt2; e += 4) {
        float p = val2[e] * inv2;
        acc += p * user_e[(size_t)list2[e] * D_ + lane];
    }
    accw[wv][lane] = acc;
    __syncthreads();                                  // barrier 5
    if (t < 64) {
        float s = accw[0][t] + accw[1][t] + accw[2][t] + accw[3][t];
        float ue = user_e[(size_t)i * D_ + t];
        out[i * D_ + t] = (4.f * ue + s) * (1.f / 3.f);
    }
}

// ---------------- Launch ----------------

extern "C" void kernel_launch(void* const* d_in, const int* in_sizes, int n_in,
                              void* d_out, int out_size, void* d_ws, size_t ws_size,
                              hipStream_t stream) {
    (void)in_sizes; (void)n_in; (void)out_size; (void)ws_size;
    const float* user_emb  = (const float*)d_in[0];
    const float* item_emb  = (const float*)d_in[1];
    const float* inter_vals= (const float*)d_in[2];
    const float* Wa        = (const float*)d_in[3];
    const float* Wb        = (const float*)d_in[4];
    const float* w1        = (const float*)d_in[5];
    const float* b1        = (const float*)d_in[6];
    const float* w2        = (const float*)d_in[7];
    const float* b2        = (const float*)d_in[8];
    const int* inter_rows  = (const int*)d_in[9];
    const int* inter_cols  = (const int*)d_in[10];
    const int* social_rows = (const int*)d_in[11];
    const int* social_cols = (const int*)d_in[12];
    float* out = (float*)d_out;

    char* w = (char*)d_ws;
    auto alloc = [&](size_t bytes) -> void* {
        void* p = (void*)w;
        w += (bytes + 255) & ~(size_t)255;
        return p;
    };
    float* h1     = (float*)alloc((size_t)N_ * D_ * 4);
    float* h2     = (float*)alloc((size_t)N_ * D_ * 4);
    float* user_e = (float*)alloc((size_t)U_ * D_ * 4);
    float* Pa     = (float*)alloc((size_t)U_ * D_ * 4);
    float* Pb     = (float*)alloc((size_t)U_ * D_ * 4);
    int*   cnt    = (int*)alloc((size_t)N_ * 4);
    int2*  ed     = (int2*)alloc((size_t)N_ * CAPI * 8);
    int*   skey   = (int*)alloc((size_t)U_ * RCAPS * 4);
    float* sval   = (float*)alloc((size_t)U_ * RCAPS * 4);

    hipMemsetAsync(cnt, 0, (size_t)N_ * 4, stream);
    hipMemsetAsync(skey, 0xFF, (size_t)U_ * RCAPS * 4, stream);  // keys = -1
    hipMemsetAsync(sval, 0, (size_t)U_ * RCAPS * 4, stream);

    // LightGCN (init fused into spmm1; hs eliminated; count+scan+scatter -> one pass)
    scatter_i_kernel<<<NEI / 256, 256, 0, stream>>>(inter_rows, inter_cols, inter_vals, cnt, ed);
    spmm1_kernel<<<N_ * 64 / 256, 256, 0, stream>>>(cnt, ed, user_emb, item_emb, h1);
    spmm2_kernel<<<N_ * 64 / 256, 256, 0, stream>>>(cnt, ed, h1, h2);
    spmm_last_kernel<<<U_ * 64 / 256, 256, 0, stream>>>(cnt, ed, user_emb, h1, h2, user_e);

    // social edge MLP -> sparse hash rows
    pab_kernel<<<U_ / 16, 256, 0, stream>>>(user_emb, Wa, Wb, w1, Pa, Pb);
    edge_kernel<<<NES * 16 / 256, 256, 0, stream>>>(social_rows, social_cols, Pa, Pb, b1, w2, b2,
                                                    skey, sval);

    // social diffusion + output
    social_kernel<<<U_, 256, 0, stream>>>(skey, sval, user_e, out);
}

// Round 5
// 237.690 us; speedup vs baseline: 3.7463x; 1.1672x over previous
//
#include <hip/hip_runtime.h>
#include <hip/hip_bf16.h>

#define U_    4096
#define I_    16384
#define D_    64
#define N_    20480     // U_ + I_
#define NEI   524288
#define NES   65536
#define CAPI  96        // interaction row-bucket capacity (mean 25.6; P(>=96) ~ 4e-25)
#define RCAPS 64        // social hash slots/row (mean nnz 16, max ~45; P(>=64) ~ 1e-18)
#define L2CAP 1536      // g2-row unique-col capacity (mean ~256, max ~800)

// ---------------- workspace init (replaces 3 memsets) ----------------
__global__ void init_ws_kernel(int* __restrict__ cnt, int* __restrict__ skey,
                               float* __restrict__ sval) {
    int tid = blockIdx.x * 256 + threadIdx.x;
    int stride = gridDim.x * 256;
    for (int o = tid; o < N_; o += stride) cnt[o] = 0;
    for (int o = tid; o < U_ * RCAPS; o += stride) { skey[o] = -1; sval[o] = 0.f; }
}

// ---------------- LightGCN: bucketed edge build ----------------

// One pass: slot = atomicAdd(count) doubles as CSR build + count.
__global__ void scatter_i_kernel(const int* __restrict__ rows, const int* __restrict__ cols,
                                 const float* __restrict__ vals,
                                 int* __restrict__ cnt, int2* __restrict__ ed) {
    int e = blockIdx.x * 256 + threadIdx.x;
    if (e >= NEI) return;
    int r = rows[e];
    int pos = atomicAdd(&cnt[r], 1);
    if (pos < CAPI) ed[(size_t)r * CAPI + pos] = make_int2(cols[e], __float_as_int(vals[e]));
}

// wave per row, lane = dim; per edge: wave-uniform int2 broadcast load + coalesced row gather.
__global__ __launch_bounds__(256) void spmm1_kernel(const int* __restrict__ cnt, const int2* __restrict__ ed,
                                                    const float* __restrict__ ue, const float* __restrict__ ie,
                                                    float* __restrict__ h1) {
    int w = (blockIdx.x * 256 + threadIdx.x) >> 6;
    int lane = threadIdx.x & 63;
    if (w >= N_) return;
    int n = cnt[w]; if (n > CAPI) n = CAPI;
    const int2* row = ed + (size_t)w * CAPI;
    float acc = 0.f;
    #pragma unroll 4
    for (int j = 0; j < n; ++j) {
        int2 e = row[j];
        int c = e.x; float v = __int_as_float(e.y);
        const float* xp = (c < U_) ? (ue + (size_t)c * D_) : (ie + (size_t)(c - U_) * D_);
        acc += v * xp[lane];
    }
    h1[(size_t)w * D_ + lane] = acc;
}

__global__ __launch_bounds__(256) void spmm2_kernel(const int* __restrict__ cnt, const int2* __restrict__ ed,
                                                    const float* __restrict__ x, float* __restrict__ y) {
    int w = (blockIdx.x * 256 + threadIdx.x) >> 6;
    int lane = threadIdx.x & 63;
    if (w >= N_) return;
    int n = cnt[w]; if (n > CAPI) n = CAPI;
    const int2* row = ed + (size_t)w * CAPI;
    float acc = 0.f;
    #pragma unroll 4
    for (int j = 0; j < n; ++j) {
        int2 e = row[j];
        acc += __int_as_float(e.y) * x[(size_t)e.x * D_ + lane];
    }
    y[(size_t)w * D_ + lane] = acc;
}

// layer 3: only user rows consumed; fuse user_e = 0.25*(e0+e1+e2+e3)
__global__ __launch_bounds__(256) void spmm_last_kernel(const int* __restrict__ cnt, const int2* __restrict__ ed,
                                                        const float* __restrict__ ue,
                                                        const float* __restrict__ h1, const float* __restrict__ h2,
                                                        float* __restrict__ user_e) {
    int w = (blockIdx.x * 256 + threadIdx.x) >> 6;
    int lane = threadIdx.x & 63;
    if (w >= U_) return;
    int n = cnt[w]; if (n > CAPI) n = CAPI;
    const int2* row = ed + (size_t)w * CAPI;
    float acc = 0.f;
    #pragma unroll 4
    for (int j = 0; j < n; ++j) {
        int2 e = row[j];
        acc += __int_as_float(e.y) * h2[(size_t)e.x * D_ + lane];
    }
    size_t o = (size_t)w * D_ + lane;
    user_e[o] = 0.25f * (ue[o] + h1[o] + h2[o] + acc);
}

// ---------------- Social edge-MLP phase ----------------

// One-shot fold: Wa2 = Wa @ w1[0:64,:], Wb2 = Wb @ w1[64:128,:]  (32 blocks)
__global__ __launch_bounds__(256) void wab2_kernel(const float* __restrict__ Wa,
                                                   const float* __restrict__ Wb,
                                                   const float* __restrict__ w1,
                                                   float* __restrict__ Wa2, float* __restrict__ Wb2) {
    int o = blockIdx.x * 256 + threadIdx.x;   // 8192 total
    int mat = o >> 12;
    int i = (o >> 6) & 63;
    int j = o & 63;
    const float* M  = mat ? Wb : Wa;
    const float* W1 = w1 + mat * 64 * 64;
    float s = 0.f;
    #pragma unroll 8
    for (int k = 0; k < 64; ++k) s += M[i * 64 + k] * W1[k * 64 + j];
    (mat ? Wb2 : Wa2)[i * 64 + j] = s;
}

// Pa = user_emb @ Wa2, Pb = user_emb @ Wb2; folded weights staged to LDS (coalesced).
__global__ __launch_bounds__(256) void pab_kernel(const float* __restrict__ ue,
                                                  const float* __restrict__ Wa2g,
                                                  const float* __restrict__ Wb2g,
                                                  float* __restrict__ Pa, float* __restrict__ Pb) {
    __shared__ float Wa2[64 * 64];
    __shared__ float Wb2[64 * 64];
    int t = threadIdx.x;
    {
        const float4* a4 = (const float4*)Wa2g;
        const float4* b4 = (const float4*)Wb2g;
        float4* A4 = (float4*)Wa2;
        float4* B4 = (float4*)Wb2;
        for (int o = t; o < 1024; o += 256) { A4[o] = a4[o]; B4[o] = b4[o]; }
    }
    __syncthreads();
    int wv = t >> 6, lane = t & 63;
    int r0 = blockIdx.x * 16;                  // 256 blocks x 16 rows
    for (int rr = wv; rr < 16; rr += 4) {
        int w = r0 + rr;
        float x = ue[w * 64 + lane];
        float accA = 0.f, accB = 0.f;
        #pragma unroll 8
        for (int k = 0; k < 64; ++k) {
            float xk = __shfl(x, k);
            accA += xk * Wa2[k * 64 + lane];
            accB += xk * Wb2[k * 64 + lane];
        }
        Pa[w * 64 + lane] = accA;
        Pb[w * 64 + lane] = accB;
    }
}

// 16 lanes per edge, float4: hid=relu(Pa[c]+Pb[r]+b1); p=hid.w2+b2; hash-insert sigmoid(p).
__global__ __launch_bounds__(256) void edge_kernel(const int* __restrict__ sr, const int* __restrict__ sc,
                                                   const float* __restrict__ Pa, const float* __restrict__ Pb,
                                                   const float* __restrict__ b1, const float* __restrict__ w2,
                                                   const float* __restrict__ b2,
                                                   int* __restrict__ skey, float* __restrict__ sval) {
    int gid = blockIdx.x * 256 + threadIdx.x;
    int w = gid >> 4;
    int q = gid & 15;
    if (w >= NES) return;
    int r = sr[w], c = sc[w];
    float4 pa = ((const float4*)Pa)[c * 16 + q];
    float4 pb = ((const float4*)Pb)[r * 16 + q];
    float4 bb = ((const float4*)b1)[q];
    float4 ww = ((const float4*)w2)[q];
    float hx = fmaxf(pa.x + pb.x + bb.x, 0.f);
    float hy = fmaxf(pa.y + pb.y + bb.y, 0.f);
    float hz = fmaxf(pa.z + pb.z + bb.z, 0.f);
    float hw = fmaxf(pa.w + pb.w + bb.w, 0.f);
    float t = hx * ww.x + hy * ww.y + hz * ww.z + hw * ww.w;
    t += __shfl_xor(t, 8);
    t += __shfl_xor(t, 4);
    t += __shfl_xor(t, 2);
    t += __shfl_xor(t, 1);
    if (q == 0) {
        float p = t + b2[0];
        float ew = 1.f / (1.f + expf(-p));
        size_t base = (size_t)r * RCAPS;
        int hh = c & (RCAPS - 1);
        for (int probe = 0; probe < RCAPS; ++probe) {
            int prev = atomicCAS(&skey[base + hh], -1, c);
            if (prev == -1 || prev == c) { atomicAdd(&sval[base + hh], ew); break; }
            hh = (hh + 1) & (RCAPS - 1);
        }
    }
}

// ---------------- Social diffusion phase ----------------

__device__ __forceinline__ float wave_max_(float v) {
    #pragma unroll
    for (int o = 32; o > 0; o >>= 1) v = fmaxf(v, __shfl_xor(v, o));
    return v;
}
__device__ __forceinline__ float wave_sum_(float v) {
    #pragma unroll
    for (int o = 32; o > 0; o >>= 1) v += __shfl_xor(v, o);
    return v;
}

// block per user row; ballot compaction, per-wave shfl softmax1 (0 barriers),
// 2-barrier softmax2. ~5 barriers total.
__global__ __launch_bounds__(256) void social_kernel(const int* __restrict__ skey,
                                                     const float* __restrict__ sval,
                                                     const float* __restrict__ user_e,
                                                     float* __restrict__ out) {
    __shared__ float row2[U_];        // 16 KB dense g2 scratch
    __shared__ int   list2[L2CAP];    // 6 KB
    __shared__ float val2[L2CAP];     // 6 KB
    __shared__ int   kcol_s[RCAPS];
    __shared__ float kval_s[RCAPS];
    __shared__ float wredm[4], wreds[4];
    __shared__ float accw[4][64];
    __shared__ int   cnt2_s, nnz_s;

    int i = blockIdx.x, t = threadIdx.x;
    int wv = t >> 6, lane = t & 63;

    for (int u = t; u < U_; u += 256) row2[u] = 0.f;
    if (t == 0) cnt2_s = 0;

    // wave 0: ballot-compact row i's hash (no atomics, no tree)
    if (wv == 0) {
        int k = skey[(size_t)i * RCAPS + lane];
        float v = sval[(size_t)i * RCAPS + lane];
        unsigned long long mask = __ballot(k >= 0);
        int pos = __popcll(mask & ((1ull << lane) - 1ull));
        if (k >= 0) { kcol_s[pos] = k; kval_s[pos] = v; }
        if (lane == 0) nnz_s = __popcll(mask);
    }
    __syncthreads();                                  // barrier 1
    int nnz = nnz_s;

    // per-wave redundant softmax1 (registers + shfl, zero barriers); nnz <= ~45 < 64
    float kv  = (lane < nnz) ? kval_s[lane] : -1e30f;
    float m1  = wave_max_(kv);
    float ex  = (lane < nnz) ? expf(kv - m1) : 0.f;
    float S1  = wave_sum_(ex);
    float inv1 = (nnz > 0) ? 1.f / S1 : 0.f;

    // g2 = sum_k A[i,k] * A[k,:] via neighbor hash rows (one 64-lane pass each)
    for (int e = wv; e < nnz; e += 4) {
        int k = kcol_s[e];
        float vk = kval_s[e];
        int   c2 = skey[(size_t)k * RCAPS + lane];
        float v2 = sval[(size_t)k * RCAPS + lane];
        if (c2 >= 0) {
            float old = atomicAdd(&row2[c2], vk * v2);
            if (old == 0.f) {                       // exactly one first-toucher
                int idx = atomicAdd(&cnt2_s, 1);
                if (idx < L2CAP) list2[idx] = c2;
            }
        }
    }

    // weighted sum 1 (independent of row2)
    float acc = 0.f;
    for (int e = wv; e < nnz; e += 4) {
        float p = __shfl(ex, e) * inv1;
        acc += p * user_e[(size_t)kcol_s[e] * D_ + lane];
    }
    __syncthreads();                                  // barrier 2 (g2 complete)

    int cnt2 = cnt2_s;
    if (cnt2 > L2CAP) cnt2 = L2CAP;

    // softmax2: per-thread partials + wave shfl + 4-entry cross-wave combine
    float lm = -1e30f;
    for (int e = t; e < cnt2; e += 256) lm = fmaxf(lm, row2[list2[e]]);
    lm = wave_max_(lm);
    if (lane == 0) wredm[wv] = lm;
    __syncthreads();                                  // barrier 3
    float m2 = fmaxf(fmaxf(wredm[0], wredm[1]), fmaxf(wredm[2], wredm[3]));
    float ls = 0.f;
    for (int e = t; e < cnt2; e += 256) {
        float exv = expf(row2[list2[e]] - m2);
        val2[e] = exv;
        ls += exv;
    }
    ls = wave_sum_(ls);
    if (lane == 0) wreds[wv] = ls;
    __syncthreads();                                  // barrier 4 (publishes val2)
    float S2 = wreds[0] + wreds[1] + wreds[2] + wreds[3];
    float inv2 = (cnt2 > 0) ? 1.f / S2 : 0.f;

    // weighted sum 2
    #pragma unroll 4
    for (int e = wv; e < cnt2; e += 4) {
        float p = val2[e] * inv2;
        acc += p * user_e[(size_t)list2[e] * D_ + lane];
    }
    accw[wv][lane] = acc;
    __syncthreads();                                  // barrier 5
    if (t < 64) {
        float s = accw[0][t] + accw[1][t] + accw[2][t] + accw[3][t];
        float ue = user_e[(size_t)i * D_ + t];
        out[i * D_ + t] = (4.f * ue + s) * (1.f / 3.f);
    }
}

// ---------------- Launch ----------------

extern "C" void kernel_launch(void* const* d_in, const int* in_sizes, int n_in,
                              void* d_out, int out_size, void* d_ws, size_t ws_size,
                              hipStream_t stream) {
    (void)in_sizes; (void)n_in; (void)out_size; (void)ws_size;
    const float* user_emb  = (const float*)d_in[0];
    const float* item_emb  = (const float*)d_in[1];
    const float* inter_vals= (const float*)d_in[2];
    const float* Wa        = (const float*)d_in[3];
    const float* Wb        = (const float*)d_in[4];
    const float* w1        = (const float*)d_in[5];
    const float* b1        = (const float*)d_in[6];
    const float* w2        = (const float*)d_in[7];
    const float* b2        = (const float*)d_in[8];
    const int* inter_rows  = (const int*)d_in[9];
    const int* inter_cols  = (const int*)d_in[10];
    const int* social_rows = (const int*)d_in[11];
    const int* social_cols = (const int*)d_in[12];
    float* out = (float*)d_out;

    char* w = (char*)d_ws;
    auto alloc = [&](size_t bytes) -> void* {
        void* p = (void*)w;
        w += (bytes + 255) & ~(size_t)255;
        return p;
    };
    float* h1     = (float*)alloc((size_t)N_ * D_ * 4);
    float* h2     = (float*)alloc((size_t)N_ * D_ * 4);
    float* user_e = (float*)alloc((size_t)U_ * D_ * 4);
    float* Pa     = (float*)alloc((size_t)U_ * D_ * 4);
    float* Pb     = (float*)alloc((size_t)U_ * D_ * 4);
    float* Wa2    = (float*)alloc(64 * 64 * 4);
    float* Wb2    = (float*)alloc(64 * 64 * 4);
    int*   cnt    = (int*)alloc((size_t)N_ * 4);
    int2*  ed     = (int2*)alloc((size_t)N_ * CAPI * 8);
    int*   skey   = (int*)alloc((size_t)U_ * RCAPS * 4);
    float* sval   = (float*)alloc((size_t)U_ * RCAPS * 4);

    init_ws_kernel<<<1024, 256, 0, stream>>>(cnt, skey, sval);

    // LightGCN (init fused into spmm1; count+scan+scatter -> one bucketed pass)
    scatter_i_kernel<<<NEI / 256, 256, 0, stream>>>(inter_rows, inter_cols, inter_vals, cnt, ed);
    spmm1_kernel<<<N_ * 64 / 256, 256, 0, stream>>>(cnt, ed, user_emb, item_emb, h1);
    spmm2_kernel<<<N_ * 64 / 256, 256, 0, stream>>>(cnt, ed, h1, h2);
    spmm_last_kernel<<<U_ * 64 / 256, 256, 0, stream>>>(cnt, ed, user_emb, h1, h2, user_e);

    // social edge MLP -> sparse hash rows
    wab2_kernel<<<32, 256, 0, stream>>>(Wa, Wb, w1, Wa2, Wb2);
    pab_kernel<<<U_ / 16, 256, 0, stream>>>(user_emb, Wa2, Wb2, Pa, Pb);
    edge_kernel<<<NES * 16 / 256, 256, 0, stream>>>(social_rows, social_cols, Pa, Pb, b1, w2, b2,
                                                    skey, sval);

    // social diffusion + output
    social_kernel<<<U_, 256, 0, stream>>>(skey, sval, user_e, out);
}